// Round 10
// baseline (30.575 us; speedup 1.0000x reference)
//
#include <hip/hip_runtime.h>
#include <math.h>

#define GRID 28
#define NP 784

// ---------- compile-time shell-sorted pair table ----------
struct PairTab { unsigned int pk[NP]; float d2[NP]; };
constexpr PairTab make_pairs() {
    PairTab t{};
    int cnt[1459] = {};
    for (int di = 0; di < GRID; ++di)
        for (int dj = 0; dj < GRID; ++dj) cnt[di*di + dj*dj]++;
    int off[1459] = {};
    int acc = 0;
    for (int s = 0; s < 1459; ++s) { off[s] = acc; acc += cnt[s]; }
    const double BY2 = (1.0/13.5) * (1.0/13.5);
    for (int di = 0; di < GRID; ++di)
        for (int dj = 0; dj < GRID; ++dj) {
            int s = di*di + dj*dj;
            int o = off[s]++;
            t.pk[o] = (unsigned)((di << 8) | dj);
            t.d2[o] = (float)((double)s * BY2);
        }
    return t;
}
__constant__ PairTab d_PT = make_pairs();

__device__ __forceinline__ void merge3(float& m0, float& m1, float& m2,
                                       float b0, float b1, float b2) {
    float r0, r1, r2;
    if (m0 <= b0) {
        r0 = m0;
        if (m1 <= b0) { r1 = m1; r2 = fminf(m2, b0); }
        else          { r1 = b0; r2 = fminf(m1, b1); }
    } else {
        r0 = b0;
        if (b1 <= m0) { r1 = b1; r2 = fminf(b2, m0); }
        else          { r1 = m0; r2 = fminf(m1, b1); }
    }
    m0 = r0; m1 = r1; m2 = r2;
}

__device__ __forceinline__ void ins3(float& m0, float& m1, float& m2, float v) {
    if (v < m0)      { m2 = m1; m1 = m0; m0 = v; }
    else if (v < m1) { m2 = m1; m1 = v; }
    else if (v < m2) { m2 = v; }
}

// ---------- conv band path: 4 output rows per block, register-rolling ----------
// smem floats: inl 240 | kAl 288 | kBl 288 | cbl 32 | h 6480 | outSm 112 = 7440
#define CB_SMEM 7440
__device__ void conv_band(const float* __restrict__ in,
                          const float* __restrict__ kA, const float* __restrict__ cbA,
                          const float* __restrict__ kB, const float* __restrict__ cbB,
                          float* __restrict__ outImg, int r0, float* smem,
                          float* __restrict__ minTrip)   // per-band min3 out (or null)
{
    float* inl   = smem;            // 240
    float* kAl   = inl + 240;       // 288
    float* kBl   = kAl + 288;       // 288
    float* cbl   = kBl + 288;       // 32
    float* h     = cbl + 32;        // 6480
    float* outSm = h + 6480;        // 112
    const int tid = threadIdx.x;
    const float cbB0 = cbB[0];

    if (tid < 288)      { kAl[tid] = kA[tid]; kBl[tid] = kB[tid]; }
    else if (tid < 320) cbl[tid - 288] = cbA[tid - 288];
    else if (tid < 560) {
        const int i = tid - 320;
        const int lr = i / 30, col = i % 30;
        const int y = r0 - 2 + lr, ix = col - 1;
        inl[i] = ((unsigned)y < GRID && (unsigned)ix < GRID) ? in[y*GRID + ix] : 0.f;
    }
    {
        float4* h4 = (float4*)h;
        for (int i = tid; i < 6480/4; i += 1024) h4[i] = make_float4(0.f,0.f,0.f,0.f);
    }
    __syncthreads();

    if (tid < 896) {
        const int c = tid & 31, xx = tid >> 5;
        float ka0 = kAl[0*32+c], ka1 = kAl[1*32+c], ka2 = kAl[2*32+c];
        float ka3 = kAl[3*32+c], ka4 = kAl[4*32+c], ka5 = kAl[5*32+c];
        float ka6 = kAl[6*32+c], ka7 = kAl[7*32+c], ka8 = kAl[8*32+c];
        const float bias = cbl[c];
        float w00 = inl[0*30+xx], w01 = inl[0*30+xx+1], w02 = inl[0*30+xx+2];
        float w10 = inl[1*30+xx], w11 = inl[1*30+xx+1], w12 = inl[1*30+xx+2];
        float w20 = inl[2*30+xx], w21 = inl[2*30+xx+1], w22 = inl[2*30+xx+2];
        #pragma unroll
        for (int s = 0; s < 6; ++s) {
            const int y = r0 - 1 + s;
            float a = bias;
            a = fmaf(w00, ka0, a); a = fmaf(w01, ka1, a); a = fmaf(w02, ka2, a);
            a = fmaf(w10, ka3, a); a = fmaf(w11, ka4, a); a = fmaf(w12, ka5, a);
            a = fmaf(w20, ka6, a); a = fmaf(w21, ka7, a); a = fmaf(w22, ka8, a);
            if ((unsigned)y < GRID) h[(s*30 + xx + 1)*36 + c] = fmaxf(a, 0.f);
            if (s < 5) {
                w00 = w10; w01 = w11; w02 = w12;
                w10 = w20; w11 = w21; w12 = w22;
                w20 = inl[(s+3)*30+xx]; w21 = inl[(s+3)*30+xx+1]; w22 = inl[(s+3)*30+xx+2];
            }
        }
    }
    __syncthreads();

    if (tid < 448) {
        const int part = tid & 3, o = tid >> 2;
        const int xx = o % 28, ly = o / 28;
        const int y = r0 + ly;
        float a = 0.f;
        #pragma unroll
        for (int dy = 0; dy < 3; ++dy) {
            #pragma unroll
            for (int dx = 0; dx < 3; ++dx) {
                const float4* hb = (const float4*)&h[((ly+dy)*30 + xx+dx)*36 + part*8];
                const float4* kb = (const float4*)&kBl[(dy*3+dx)*32 + part*8];
                const float4 h0 = hb[0], h1 = hb[1];
                const float4 k0 = kb[0], k1 = kb[1];
                a += h0.x*k0.x; a += h0.y*k0.y; a += h0.z*k0.z; a += h0.w*k0.w;
                a += h1.x*k1.x; a += h1.y*k1.y; a += h1.z*k1.z; a += h1.w*k1.w;
            }
        }
        a += __shfl_xor(a, 1, 64);
        a += __shfl_xor(a, 2, 64);
        if (part == 0) {
            const float v = fmaxf(a + cbB0, 0.f);
            outImg[y*GRID + xx] = v;
            if (minTrip) outSm[o] = v;
        }
    }

    // per-band min3 over the 112 outputs (multiset-invariant partial)
    if (minTrip) {
        __syncthreads();
        if (tid < 64) {
            float m0 = INFINITY, m1 = INFINITY, m2 = INFINITY;
            ins3(m0, m1, m2, outSm[tid]);
            if (tid < 48) ins3(m0, m1, m2, outSm[64 + tid]);
            for (int mask = 1; mask <= 32; mask <<= 1) {
                const float b0 = __shfl_xor(m0, mask, 64);
                const float b1 = __shfl_xor(m1, mask, 64);
                const float b2 = __shfl_xor(m2, mask, 64);
                merge3(m0, m1, m2, b0, b1, b2);
            }
            if (tid == 0) { minTrip[0] = m0; minTrip[1] = m1; minTrip[2] = m2; }
        }
    }
}

// ---------- K1: conv1 (112 blocks) + dtm (392 blocks x 2 images) = 504 blocks ----------
// 504 blocks <= 512 resident (2 blocks/CU) -> single dispatch round.
__global__ __launch_bounds__(1024, 8) void k1_kernel(const float* __restrict__ x,
        const float* __restrict__ k11, const float* __restrict__ cb11,
        const float* __restrict__ k12, const float* __restrict__ cb12,
        float* __restrict__ ws)
{
    __shared__ float smem[CB_SMEM];
    const int blk = blockIdx.x;
    const int tid = threadIdx.x;

    if (blk < 112) {                      // conv1: x -> x1o
        const int img = blk / 7, band = blk % 7;
        conv_band(x + img*NP, k11, cb11, k12, cb12, ws + 25088 + img*NP, band*4, smem,
                  (float*)0);
        return;
    }

    // ---- dtm: block handles images 2a and 2a+1, group grp ----
    float* wimg = smem;
    float* red  = smem + 784;
    float* out1 = ws;
    float* out2 = ws + 12544;
    const int dblk = blk - 112;           // [0,392)
    const int a = dblk / 49, grp = dblk % 49;
    const int w = tid >> 6, lane = tid & 63;
    const int pix = grp*16 + w;
    const int pr = pix / GRID, pc = pix % GRID;

    #pragma unroll
    for (int sub = 0; sub < 2; ++sub) {
        const int img = a*2 + sub;
        if (sub) __syncthreads();         // prior scan's wimg readers done
        float v = 0.f;
        if (tid < NP) { v = x[img*NP + tid]; wimg[tid] = v; }
        for (int off = 32; off; off >>= 1) v += __shfl_down(v, off, 64);
        if (lane == 0) red[w] = v;
        __syncthreads();                  // wimg + red ready
        float sumw = 0.f;
        #pragma unroll
        for (int i = 0; i < 16; ++i) sumw += red[i];

        const float m0W1 = 0.05f * sumw;
        const float m0W2 = 0.2f  * sumw;
        float a1 = 0.f, a2 = 0.f, carry = 0.f;

        for (int k0 = 0; k0 < NP; k0 += 64) {
            const int idx = k0 + lane;
            const int ii  = idx < NP ? idx : NP-1;
            const unsigned p = d_PT.pk[ii];
            const float dd   = d_PT.d2[ii];
            const int di = (int)(p >> 8);
            const int dj = (int)(p & 255u);
            const int dG = di * GRID;
            const bool rpOK = (pr + di) < GRID;
            const bool rmOK = pr >= di;
            const bool cpOK = (pc + dj) < GRID;
            const bool cmOK = pc >= dj;
            float Wg = 0.f;
            if (rpOK && cpOK)               Wg += wimg[pix + dG + dj];
            if (dj && rpOK && cmOK)         Wg += wimg[pix + dG - dj];
            if (di && rmOK && cpOK)         Wg += wimg[pix - dG + dj];
            if (di && dj && rmOK && cmOK)   Wg += wimg[pix - dG - dj];
            if (idx >= NP) Wg = 0.f;
            float incl = Wg;
            #pragma unroll
            for (int d = 1; d < 64; d <<= 1) {
                const float t = __shfl_up(incl, d, 64);
                if (lane >= d) incl += t;
            }
            const float cumb = carry + (incl - Wg);
            const float e1 = fminf(fmaxf(m0W1 - cumb, 0.f), Wg);
            const float e2 = fminf(fmaxf(m0W2 - cumb, 0.f), Wg);
            a1 = fmaf(e1, dd, a1);
            a2 = fmaf(e2, dd, a2);
            carry += __shfl(incl, 63, 64);
            if (carry >= m0W2) break;
        }
        for (int m = 32; m; m >>= 1) { a1 += __shfl_xor(a1, m, 64); a2 += __shfl_xor(a2, m, 64); }
        if (lane == 0) {
            out1[img*NP + pix] = sqrtf(a1 / m0W1);
            out2[img*NP + pix] = sqrtf(a2 / m0W2);
        }
    }
}

__device__ __forceinline__ float tseqA(int i) {
    if (i == 24) return 0.3f;
    return (float)((double)i * ((0.3 - 0.06)/24.0) + 0.06);
}
__device__ __forceinline__ float tseqB(int i) {
    if (i == 26) return 0.4f;
    return (float)((double)i * ((0.4 - 0.14)/26.0) + 0.14);
}

// topo partial for one wave holding f0,f1,f2 in all lanes (g=lane>>4, j=lane&15)
__device__ __forceinline__ float topoA_partial(const float* __restrict__ Wm,
                                               float f0, float f1, int lane) {
    const int g = lane >> 4, j = lane & 15;
    float at = 0.f;
    #pragma unroll
    for (int r = 0; r < 13; ++r) {
        const int i = g + 4*r;
        if (i < 50) {
            const int t = i >> 1, k = i & 1;
            const float ts = tseqA(t);
            const float fk = k ? f1 : f0;
            const float lam = fmaxf(fminf(ts - fk, 0.3f - ts), 0.f);
            at = fmaf(lam, Wm[i*16 + j], at);
        }
    }
    return at;
}
__device__ __forceinline__ float topoB_partial(const float* __restrict__ Wm,
                                               float f0, float f1, float f2, int lane) {
    const int g = lane >> 4, j = lane & 15;
    float at = 0.f;
    #pragma unroll
    for (int r = 0; r < 21; ++r) {
        const int i = g + 4*r;
        if (i < 81) {
            const int t = i / 3, k = i - t*3;
            const float ts = tseqB(t);
            const float fk = (k == 0) ? f0 : (k == 1 ? f1 : f2);
            const float lam = fmaxf(fminf(ts - fk, 0.4f - ts), 0.f);
            at = fmaf(lam, Wm[i*16 + j], at);
        }
    }
    return at;
}

// ---------- K2: conv3/conv4 bands (224) + topo5/topo6 blocks (32) ----------
// ws slots: trip3 @62720 [16][7][3], trip4 @63056, topo5 @63392 [16][16], topo6 @63648
__global__ __launch_bounds__(1024, 8) void k2_kernel(
        const float* __restrict__ k31, const float* __restrict__ cb31,
        const float* __restrict__ k32, const float* __restrict__ cb32,
        const float* __restrict__ k41, const float* __restrict__ cb41,
        const float* __restrict__ k42, const float* __restrict__ cb42,
        const float* __restrict__ W5,  const float* __restrict__ b5,
        const float* __restrict__ W6,  const float* __restrict__ b6,
        float* __restrict__ ws)
{
    __shared__ float smem[CB_SMEM];
    const int blk = blockIdx.x;
    const int tid = threadIdx.x;
    const float* x2_1 = ws;
    const float* x2_2 = ws + 12544;
    float* x3c   = ws + 37632;
    float* x4c   = ws + 50176;
    float* trip3 = ws + 62720;
    float* trip4 = ws + 63056;
    float* topo5 = ws + 63392;
    float* topo6 = ws + 63648;

    if (blk < 112) {
        const int img = blk / 7, band = blk % 7;
        conv_band(x2_1 + img*NP, k31, cb31, k32, cb32, x3c + img*NP, band*4, smem,
                  trip3 + (img*7 + band)*3);
    } else if (blk < 224) {
        const int c = blk - 112;
        const int img = c / 7, band = c % 7;
        conv_band(x2_2 + img*NP, k41, cb41, k42, cb42, x4c + img*NP, band*4, smem,
                  trip4 + (img*7 + band)*3);
    } else {
        // topo5/topo6: wave 0 only; min3 partition identical to R5 (k*64+lane)
        if (tid >= 64) return;
        const int idx = blk - 224;
        const int arr = idx >> 4, img = idx & 15;
        const float* src = (arr == 0) ? (x2_1 + img*NP) : (x2_2 + img*NP);
        const int lane = tid;
        float m0 = INFINITY, m1 = INFINITY, m2 = INFINITY;
        #pragma unroll
        for (int k = 0; k < 13; ++k) {
            const int i = k*64 + lane;
            const float v = (i < NP) ? src[i] : INFINITY;
            ins3(m0, m1, m2, v);
        }
        for (int mask = 1; mask <= 32; mask <<= 1) {
            const float b0 = __shfl_xor(m0, mask, 64);
            const float b1 = __shfl_xor(m1, mask, 64);
            const float b2 = __shfl_xor(m2, mask, 64);
            merge3(m0, m1, m2, b0, b1, b2);
        }
        float at = (arr == 0) ? topoA_partial(W5, m0, m1, lane)
                              : topoB_partial(W6, m0, m1, m2, lane);
        at += __shfl_xor(at, 16, 64);
        at += __shfl_xor(at, 32, 64);
        if (lane < 16) {
            const float* bv = (arr == 0) ? b5 : b6;
            float* dst = (arr == 0) ? topo5 : topo6;
            dst[img*16 + lane] = fmaxf(at + bv[lane], 0.f);
        }
    }
}

// ---------- K3: latency-flat tail — W7 in regs, one barrier, single FMA chain ----------
__global__ __launch_bounds__(1024) void tail_kernel(
        const float* __restrict__ W33, const float* __restrict__ b33,
        const float* __restrict__ W43, const float* __restrict__ b43,
        const float* __restrict__ W7,  const float* __restrict__ b7,
        const float* __restrict__ W8,  const float* __restrict__ b8,
        const float* __restrict__ ws,  float* __restrict__ out)
{
    __shared__ float xc[848];
    __shared__ float part[1024];
    __shared__ float h7f[64];
    const int b = blockIdx.x, tid = threadIdx.x;
    const int w = tid >> 6, lane = tid & 63;
    const float* x1o   = ws + 25088;
    const float* trip3 = ws + 62720;
    const float* trip4 = ws + 63056;
    const float* topo5 = ws + 63392;
    const float* topo6 = ws + 63648;

    // 1) issue W7 loads into registers up-front (independent of everything)
    float w7r[53];
    {
        const float* Wp = W7 + (w * 53) * 64 + lane;
        #pragma unroll
        for (int r = 0; r < 53; ++r) w7r[r] = Wp[r*64];
    }

    // 2) stage xc body + topo5/6 copies (independent)
    if (tid < NP) xc[tid] = x1o[b*NP + tid];
    if (w == 2 && lane < 16) xc[816 + lane] = topo5[b*16 + lane];
    if (w == 3 && lane < 16) xc[832 + lane] = topo6[b*16 + lane];

    // 3) waves 0/1: merge 7 triples (uniform scalar loads, every lane redundant)
    //    then topo3/4 partial + reduce
    if (w < 2) {
        const float* tp = ((w == 0) ? trip3 : trip4) + b*21;
        float m0 = tp[0], m1 = tp[1], m2 = tp[2];
        #pragma unroll
        for (int s = 1; s < 7; ++s)
            merge3(m0, m1, m2, tp[s*3], tp[s*3+1], tp[s*3+2]);
        float at = (w == 0) ? topoA_partial(W33, m0, m1, lane)
                            : topoB_partial(W43, m0, m1, m2, lane);
        at += __shfl_xor(at, 16, 64);
        at += __shfl_xor(at, 32, 64);
        if (lane < 16) {
            const float* bv = (w == 0) ? b33 : b43;
            xc[784 + w*16 + lane] = fmaxf(at + bv[lane], 0.f);
        }
    }
    __syncthreads();                     // xc fully written

    // 4) single ascending FMA chain (same contraction order as before)
    {
        float acc = 0.f;
        const int i0 = w * 53;
        #pragma unroll
        for (int r = 0; r < 53; ++r)
            acc = fmaf(xc[i0 + r], w7r[r], acc);
        part[w*64 + lane] = acc;
    }
    __syncthreads();
    if (tid < 64) {
        float s = b7[tid];
        #pragma unroll
        for (int k = 0; k < 16; ++k) s += part[k*64 + tid];
        h7f[tid] = fmaxf(s, 0.f);
    }
    __syncthreads();

    if (w < 10) {
        float a2 = h7f[lane] * W8[lane*10 + w];
        for (int m = 32; m; m >>= 1) a2 += __shfl_down(a2, m, 64);
        if (lane == 0) out[b*10 + w] = a2 + b8[w];
    }
}

extern "C" void kernel_launch(void* const* d_in, const int* in_sizes, int n_in,
                              void* d_out, int out_size, void* d_ws, size_t ws_size,
                              hipStream_t stream)
{
    const float* x    = (const float*)d_in[0];
    const float* k11  = (const float*)d_in[1];
    const float* cb11 = (const float*)d_in[2];
    const float* k12  = (const float*)d_in[3];
    const float* cb12 = (const float*)d_in[4];
    const float* k31  = (const float*)d_in[5];
    const float* cb31 = (const float*)d_in[6];
    const float* k32  = (const float*)d_in[7];
    const float* cb32 = (const float*)d_in[8];
    const float* k41  = (const float*)d_in[9];
    const float* cb41 = (const float*)d_in[10];
    const float* k42  = (const float*)d_in[11];
    const float* cb42 = (const float*)d_in[12];
    const float* W33  = (const float*)d_in[13];
    const float* b33  = (const float*)d_in[14];
    const float* W43  = (const float*)d_in[15];
    const float* b43  = (const float*)d_in[16];
    const float* W5   = (const float*)d_in[17];
    const float* b5   = (const float*)d_in[18];
    const float* W6   = (const float*)d_in[19];
    const float* b6   = (const float*)d_in[20];
    const float* W7   = (const float*)d_in[21];
    const float* b7   = (const float*)d_in[22];
    const float* W8   = (const float*)d_in[23];
    const float* b8   = (const float*)d_in[24];
    float* ws  = (float*)d_ws;
    float* out = (float*)d_out;

    k1_kernel  <<<dim3(504), dim3(1024), 0, stream>>>(x, k11, cb11, k12, cb12, ws);
    k2_kernel  <<<dim3(256), dim3(1024), 0, stream>>>(k31, cb31, k32, cb32,
                                                      k41, cb41, k42, cb42,
                                                      W5, b5, W6, b6, ws);
    tail_kernel<<<dim3(16),  dim3(1024), 0, stream>>>(W33, b33, W43, b43,
                                                      W7, b7, W8, b8, ws, out);
}

// Round 11
// 29.247 us; speedup vs baseline: 1.0454x; 1.0454x over previous
//
#include <hip/hip_runtime.h>
#include <math.h>

#define GRID 28
#define NP 784

// ---------- compile-time shell-sorted pair table ----------
// pk = di<<8 | dj   (s = di^2+dj^2 ascending);  d2 = s * BY^2
struct PairTab { unsigned int pk[NP]; float d2[NP]; };
constexpr PairTab make_pairs() {
    PairTab t{};
    int cnt[1459] = {};
    for (int di = 0; di < GRID; ++di)
        for (int dj = 0; dj < GRID; ++dj) cnt[di*di + dj*dj]++;
    int off[1459] = {};
    int acc = 0;
    for (int s = 0; s < 1459; ++s) { off[s] = acc; acc += cnt[s]; }
    const double BY2 = (1.0/13.5) * (1.0/13.5);
    for (int di = 0; di < GRID; ++di)
        for (int dj = 0; dj < GRID; ++dj) {
            int s = di*di + dj*dj;
            int o = off[s]++;
            t.pk[o] = (unsigned)((di << 8) | dj);
            t.d2[o] = (float)((double)s * BY2);
        }
    return t;
}
__constant__ PairTab d_PT = make_pairs();

// ---------- conv band path: 4 output rows per block, register-rolling ----------
// LDS: inl [8][30] zero-padded cols; h [6][30][36] (36-stride, 16B aligned, halos 0)
// smem floats: inl 240 | kAl 288 | kBl 288 | cbl 32 | h 6480  = 7328
#define CB_SMEM 7328
__device__ void conv_band(const float* __restrict__ in,
                          const float* __restrict__ kA, const float* __restrict__ cbA,
                          const float* __restrict__ kB, const float* __restrict__ cbB,
                          float* __restrict__ outImg, int r0, float* smem)
{
    float* inl = smem;            // 240
    float* kAl = inl + 240;       // 288
    float* kBl = kAl + 288;       // 288
    float* cbl = kBl + 288;       // 32
    float* h   = cbl + 32;        // 6480
    const int tid = threadIdx.x;
    const float cbB0 = cbB[0];

    if (tid < 288)      { kAl[tid] = kA[tid]; kBl[tid] = kB[tid]; }
    else if (tid < 320) cbl[tid - 288] = cbA[tid - 288];
    else if (tid < 560) {
        const int i = tid - 320;
        const int lr = i / 30, col = i % 30;
        const int y = r0 - 2 + lr, ix = col - 1;
        inl[i] = ((unsigned)y < GRID && (unsigned)ix < GRID) ? in[y*GRID + ix] : 0.f;
    }
    // zero h (halos must be 0; interior gets overwritten)
    {
        float4* h4 = (float4*)h;
        for (int i = tid; i < 6480/4; i += 1024) h4[i] = make_float4(0.f,0.f,0.f,0.f);
    }
    __syncthreads();

    // ---- convA: thread = (c, xx); walk 6 h-rows with rolling 3x3 window ----
    if (tid < 896) {
        const int c = tid & 31, xx = tid >> 5;       // xx in [0,28)
        float ka0 = kAl[0*32+c], ka1 = kAl[1*32+c], ka2 = kAl[2*32+c];
        float ka3 = kAl[3*32+c], ka4 = kAl[4*32+c], ka5 = kAl[5*32+c];
        float ka6 = kAl[6*32+c], ka7 = kAl[7*32+c], ka8 = kAl[8*32+c];
        const float bias = cbl[c];
        float w00 = inl[0*30+xx], w01 = inl[0*30+xx+1], w02 = inl[0*30+xx+2];
        float w10 = inl[1*30+xx], w11 = inl[1*30+xx+1], w12 = inl[1*30+xx+2];
        float w20 = inl[2*30+xx], w21 = inl[2*30+xx+1], w22 = inl[2*30+xx+2];
        #pragma unroll
        for (int s = 0; s < 6; ++s) {
            const int y = r0 - 1 + s;                // wave-uniform
            float a = bias;
            a = fmaf(w00, ka0, a); a = fmaf(w01, ka1, a); a = fmaf(w02, ka2, a);
            a = fmaf(w10, ka3, a); a = fmaf(w11, ka4, a); a = fmaf(w12, ka5, a);
            a = fmaf(w20, ka6, a); a = fmaf(w21, ka7, a); a = fmaf(w22, ka8, a);
            if ((unsigned)y < GRID) h[(s*30 + xx + 1)*36 + c] = fmaxf(a, 0.f);
            if (s < 5) {
                w00 = w10; w01 = w11; w02 = w12;
                w10 = w20; w11 = w21; w12 = w22;
                w20 = inl[(s+3)*30+xx]; w21 = inl[(s+3)*30+xx+1]; w22 = inl[(s+3)*30+xx+2];
            }
        }
    }
    __syncthreads();

    // ---- convB: 4 rows x 28 outputs, 4 lanes/output (8-ch partials), no bounds ----
    if (tid < 448) {
        const int part = tid & 3, o = tid >> 2;
        const int xx = o % 28, ly = o / 28;
        const int y = r0 + ly;
        float a = 0.f;
        #pragma unroll
        for (int dy = 0; dy < 3; ++dy) {
            #pragma unroll
            for (int dx = 0; dx < 3; ++dx) {
                const float4* hb = (const float4*)&h[((ly+dy)*30 + xx+dx)*36 + part*8];
                const float4* kb = (const float4*)&kBl[(dy*3+dx)*32 + part*8];
                const float4 h0 = hb[0], h1 = hb[1];
                const float4 k0 = kb[0], k1 = kb[1];
                a += h0.x*k0.x; a += h0.y*k0.y; a += h0.z*k0.z; a += h0.w*k0.w;
                a += h1.x*k1.x; a += h1.y*k1.y; a += h1.z*k1.z; a += h1.w*k1.w;
            }
        }
        a += __shfl_xor(a, 1, 64);
        a += __shfl_xor(a, 2, 64);
        if (part == 0) outImg[y*GRID + xx] = fmaxf(a + cbB0, 0.f);
    }
}

// ---------- K1: conv1 (112 blocks, independent of dtm) + dtm (784 blocks) ----------
__global__ __launch_bounds__(1024, 8) void k1_kernel(const float* __restrict__ x,
        const float* __restrict__ k11, const float* __restrict__ cb11,
        const float* __restrict__ k12, const float* __restrict__ cb12,
        float* __restrict__ ws)
{
    __shared__ float smem[CB_SMEM];
    const int blk = blockIdx.x;
    const int tid = threadIdx.x;

    if (blk < 112) {                      // conv1: x -> x1o
        const int img = blk / 7, band = blk % 7;
        conv_band(x + img*NP, k11, cb11, k12, cb12, ws + 25088 + img*NP, band*4, smem);
        return;
    }

    // ---- dtm ----
    float* wimg = smem;                   // 784
    float* red  = smem + 784;             // 16
    float* out1 = ws;
    float* out2 = ws + 12544;
    const int dblk = blk - 112;
    const int img = dblk / 49, grp = dblk % 49;
    const int w = tid >> 6, lane = tid & 63;

    float v = 0.f;
    if (tid < NP) { v = x[img*NP + tid]; wimg[tid] = v; }
    for (int off = 32; off; off >>= 1) v += __shfl_down(v, off, 64);
    if (lane == 0) red[w] = v;
    __syncthreads();                     // wimg + red ready
    float sumw = 0.f;
    #pragma unroll
    for (int i = 0; i < 16; ++i) sumw += red[i];   // waves 13-15 contributed 0

    const int pix = grp*16 + w;                    // uniform per wave
    const int pr = pix / GRID, pc = pix % GRID;
    const float m0W1 = 0.05f * sumw;
    const float m0W2 = 0.2f  * sumw;
    float a1 = 0.f, a2 = 0.f, carry = 0.f;

    for (int k0 = 0; k0 < NP; k0 += 64) {
        const int idx = k0 + lane;
        const int ii  = idx < NP ? idx : NP-1;
        const unsigned p = d_PT.pk[ii];
        const float dd   = d_PT.d2[ii];
        const int di = (int)(p >> 8);
        const int dj = (int)(p & 255u);
        const int dG = di * GRID;
        const bool rpOK = (pr + di) < GRID;
        const bool rmOK = pr >= di;
        const bool cpOK = (pc + dj) < GRID;
        const bool cmOK = pc >= dj;
        float Wg = 0.f;
        if (rpOK && cpOK)               Wg += wimg[pix + dG + dj];
        if (dj && rpOK && cmOK)         Wg += wimg[pix + dG - dj];
        if (di && rmOK && cpOK)         Wg += wimg[pix - dG + dj];
        if (di && dj && rmOK && cmOK)   Wg += wimg[pix - dG - dj];
        if (idx >= NP) Wg = 0.f;
        // inclusive scan of Wg across the wave
        float incl = Wg;
        #pragma unroll
        for (int d = 1; d < 64; d <<= 1) {
            const float t = __shfl_up(incl, d, 64);
            if (lane >= d) incl += t;
        }
        const float cumb = carry + (incl - Wg);    // exclusive cumsum before this pair
        const float e1 = fminf(fmaxf(m0W1 - cumb, 0.f), Wg);
        const float e2 = fminf(fmaxf(m0W2 - cumb, 0.f), Wg);
        a1 = fmaf(e1, dd, a1);
        a2 = fmaf(e2, dd, a2);
        carry += __shfl(incl, 63, 64);
        if (carry >= m0W2) break;                  // uniform: all later eff are 0
    }
    for (int m = 32; m; m >>= 1) { a1 += __shfl_xor(a1, m, 64); a2 += __shfl_xor(a2, m, 64); }
    if (lane == 0) {
        out1[img*NP + pix] = sqrtf(a1 / m0W1);
        out2[img*NP + pix] = sqrtf(a2 / m0W2);
    }
}

// ---------- K2: conv3 + conv4 band paths (224 blocks) ----------
__global__ __launch_bounds__(1024, 8) void k2_kernel(
        const float* __restrict__ k31, const float* __restrict__ cb31,
        const float* __restrict__ k32, const float* __restrict__ cb32,
        const float* __restrict__ k41, const float* __restrict__ cb41,
        const float* __restrict__ k42, const float* __restrict__ cb42,
        float* __restrict__ ws)
{
    __shared__ float smem[CB_SMEM];
    const int blk = blockIdx.x;
    const float* x2_1 = ws;
    const float* x2_2 = ws + 12544;
    float* x3c = ws + 37632;
    float* x4c = ws + 50176;

    if (blk < 112) {
        const int img = blk / 7, band = blk % 7;
        conv_band(x2_1 + img*NP, k31, cb31, k32, cb32, x3c + img*NP, band*4, smem);
    } else {
        const int c = blk - 112;
        const int img = c / 7, band = c % 7;
        conv_band(x2_2 + img*NP, k41, cb41, k42, cb42, x4c + img*NP, band*4, smem);
    }
}

__device__ __forceinline__ float tseqA(int i) {
    if (i == 24) return 0.3f;
    return (float)((double)i * ((0.3 - 0.06)/24.0) + 0.06);
}
__device__ __forceinline__ float tseqB(int i) {
    if (i == 26) return 0.4f;
    return (float)((double)i * ((0.4 - 0.14)/26.0) + 0.14);
}

__device__ __forceinline__ void merge3(float& m0, float& m1, float& m2,
                                       float b0, float b1, float b2) {
    float r0, r1, r2;
    if (m0 <= b0) {
        r0 = m0;
        if (m1 <= b0) { r1 = m1; r2 = fminf(m2, b0); }
        else          { r1 = b0; r2 = fminf(m1, b1); }
    } else {
        r0 = b0;
        if (b1 <= m0) { r1 = b1; r2 = fminf(b2, m0); }
        else          { r1 = m0; r2 = fminf(m1, b1); }
    }
    m0 = r0; m1 = r1; m2 = r2;
}

__device__ __forceinline__ void ins3(float& m0, float& m1, float& m2, float v) {
    if (v < m0)      { m2 = m1; m1 = m0; m0 = v; }
    else if (v < m1) { m2 = m1; m1 = v; }
    else if (v < m2) { m2 = v; }
}

// ---------- K3: topo features + final MLP, one block per image (1024 thr) ----------
// latency-batched — all global-load loops unrolled/front-loaded; topo weights in LDS.
__global__ __launch_bounds__(1024) void tail_kernel(
        const float* __restrict__ W33, const float* __restrict__ b33,
        const float* __restrict__ W43, const float* __restrict__ b43,
        const float* __restrict__ W5,  const float* __restrict__ b5,
        const float* __restrict__ W6,  const float* __restrict__ b6,
        const float* __restrict__ W7,  const float* __restrict__ b7,
        const float* __restrict__ W8,  const float* __restrict__ b8,
        const float* __restrict__ ws,  float* __restrict__ out)
{
    __shared__ float xc[848];
    __shared__ float Wsm[4192];          // W33[800] | W43[1296] | W5[800] | W6[1296]
    __shared__ float part[1024];
    __shared__ float h7[64];
    __shared__ float fsh[64];            // [0..48): 16 partial triples; [48..60): final triples
    const int b = blockIdx.x, tid = threadIdx.x;
    const int w = tid >> 6, lane = tid & 63;
    const float* x2_1 = ws;
    const float* x2_2 = ws + 12544;
    const float* x1o  = ws + 25088;
    const float* x3c  = ws + 37632;
    const float* x4c  = ws + 50176;

    if (tid < NP) xc[tid] = x1o[b*NP + tid];

    // stage topo weight matrices into LDS (coalesced)
    for (int i = tid; i < 4192; i += 1024) {
        float v;
        if (i < 800)       v = W33[i];
        else if (i < 2096) v = W43[i - 800];
        else if (i < 2896) v = W5[i - 2096];
        else               v = W6[i - 2896];
        Wsm[i] = v;
    }

    // min3: 16 waves = 4 arrays x 4 segments of 196; loads issued up-front
    {
        const int arr = w >> 2, seg = w & 3;
        const float* src = (arr == 0) ? x3c : (arr == 1) ? x4c : (arr == 2) ? x2_1 : x2_2;
        src += b*NP + seg*196;
        const float v0 = src[lane];
        const float v1 = src[lane + 64];
        const float v2 = src[lane + 128];
        const float v3 = (lane < 4) ? src[lane + 192] : INFINITY;
        float m0 = INFINITY, m1 = INFINITY, m2 = INFINITY;
        ins3(m0, m1, m2, v0);
        ins3(m0, m1, m2, v1);
        ins3(m0, m1, m2, v2);
        ins3(m0, m1, m2, v3);
        for (int mask = 1; mask <= 32; mask <<= 1) {
            const float b0 = __shfl_xor(m0, mask, 64);
            const float b1 = __shfl_xor(m1, mask, 64);
            const float b2 = __shfl_xor(m2, mask, 64);
            merge3(m0, m1, m2, b0, b1, b2);
        }
        if (lane == 0) { fsh[w*3+0] = m0; fsh[w*3+1] = m1; fsh[w*3+2] = m2; }
    }
    __syncthreads();
    if (tid < 4) {                       // merge the 4 segment-triples of array `tid`
        float m0 = fsh[(tid*4+0)*3+0], m1 = fsh[(tid*4+0)*3+1], m2 = fsh[(tid*4+0)*3+2];
        #pragma unroll
        for (int s = 1; s < 4; ++s)
            merge3(m0, m1, m2, fsh[(tid*4+s)*3+0], fsh[(tid*4+s)*3+1], fsh[(tid*4+s)*3+2]);
        fsh[48 + tid*3 + 0] = m0; fsh[48 + tid*3 + 1] = m1; fsh[48 + tid*3 + 2] = m2;
    }
    __syncthreads();

    // topo matvecs: waves 0-3, lanes = 4 i-groups x 16 j; weights from LDS
    if (w < 4) {
        const int g = lane >> 4, j = lane & 15;
        const float f0 = fsh[48 + w*3 + 0], f1 = fsh[48 + w*3 + 1], f2 = fsh[48 + w*3 + 2];
        float acc = 0.f;
        if (w == 0 || w == 2) {               // A: T=25, K=2 -> 50 terms
            const float* Wm = (w == 0) ? &Wsm[0] : &Wsm[2096];
            for (int i = g; i < 50; i += 4) {
                const int t = i >> 1, k = i & 1;
                const float ts = tseqA(t);
                const float fk = k ? f1 : f0;
                const float lam = fmaxf(fminf(ts - fk, 0.3f - ts), 0.f);
                acc = fmaf(lam, Wm[i*16 + j], acc);
            }
        } else {                              // B: T=27, K=3 -> 81 terms
            const float* Wm = (w == 1) ? &Wsm[800] : &Wsm[2896];
            for (int i = g; i < 81; i += 4) {
                const int t = i / 3, k = i - t*3;
                const float ts = tseqB(t);
                const float fk = (k == 0) ? f0 : (k == 1 ? f1 : f2);
                const float lam = fmaxf(fminf(ts - fk, 0.4f - ts), 0.f);
                acc = fmaf(lam, Wm[i*16 + j], acc);
            }
        }
        acc += __shfl_xor(acc, 16, 64);
        acc += __shfl_xor(acc, 32, 64);
        if (lane < 16) {
            const float* bv = (w == 0) ? b33 : (w == 1) ? b43 : (w == 2) ? b5 : b6;
            xc[784 + w*16 + lane] = fmaxf(acc + bv[lane], 0.f);
        }
    }
    __syncthreads();

    // relu(xc @ W7 + b7): constant-trip full unroll so the 53 independent W7
    // loads get hoisted/batched (single acc: bitwise-same order)
    {
        float acc = 0.f;
        const int i0 = w * 53;
        const float* Wp = W7 + i0*64 + lane;
        #pragma unroll
        for (int r = 0; r < 53; ++r)
            acc = fmaf(xc[i0 + r], Wp[r*64], acc);
        part[w*64 + lane] = acc;
    }
    __syncthreads();
    if (tid < 64) {
        float s = b7[tid];
        #pragma unroll
        for (int k = 0; k < 16; ++k) s += part[k*64 + tid];
        h7[tid] = fmaxf(s, 0.f);
    }
    __syncthreads();

    // @ W8 + b8: wave w computes output w (10 waves), butterfly reduce
    if (w < 10) {
        float a2 = h7[lane] * W8[lane*10 + w];
        for (int m = 32; m; m >>= 1) a2 += __shfl_down(a2, m, 64);
        if (lane == 0) out[b*10 + w] = a2 + b8[w];
    }
}

extern "C" void kernel_launch(void* const* d_in, const int* in_sizes, int n_in,
                              void* d_out, int out_size, void* d_ws, size_t ws_size,
                              hipStream_t stream)
{
    const float* x    = (const float*)d_in[0];
    const float* k11  = (const float*)d_in[1];
    const float* cb11 = (const float*)d_in[2];
    const float* k12  = (const float*)d_in[3];
    const float* cb12 = (const float*)d_in[4];
    const float* k31  = (const float*)d_in[5];
    const float* cb31 = (const float*)d_in[6];
    const float* k32  = (const float*)d_in[7];
    const float* cb32 = (const float*)d_in[8];
    const float* k41  = (const float*)d_in[9];
    const float* cb41 = (const float*)d_in[10];
    const float* k42  = (const float*)d_in[11];
    const float* cb42 = (const float*)d_in[12];
    const float* W33  = (const float*)d_in[13];
    const float* b33  = (const float*)d_in[14];
    const float* W43  = (const float*)d_in[15];
    const float* b43  = (const float*)d_in[16];
    const float* W5   = (const float*)d_in[17];
    const float* b5   = (const float*)d_in[18];
    const float* W6   = (const float*)d_in[19];
    const float* b6   = (const float*)d_in[20];
    const float* W7   = (const float*)d_in[21];
    const float* b7   = (const float*)d_in[22];
    const float* W8   = (const float*)d_in[23];
    const float* b8   = (const float*)d_in[24];
    float* ws  = (float*)d_ws;
    float* out = (float*)d_out;

    k1_kernel  <<<dim3(896), dim3(1024), 0, stream>>>(x, k11, cb11, k12, cb12, ws);
    k2_kernel  <<<dim3(224), dim3(1024), 0, stream>>>(k31, cb31, k32, cb32,
                                                      k41, cb41, k42, cb42, ws);
    tail_kernel<<<dim3(16),  dim3(1024), 0, stream>>>(W33, b33, W43, b43, W5, b5, W6, b6,
                                                      W7, b7, W8, b8, ws, out);
}